// Round 8
// baseline (212.113 us; speedup 1.0000x reference)
//
#include <hip/hip_runtime.h>
#include <hip/hip_bf16.h>

#define DEV __device__ __forceinline__

typedef unsigned short u16;
typedef unsigned int u32;
typedef __attribute__((ext_vector_type(8))) short short8;
typedef __attribute__((ext_vector_type(4))) float f32x4;

DEV u16 f2bf(float f) {
  __hip_bfloat16 h = __float2bfloat16(f);   // RNE; pairs into v_cvt_pk_bf16_f32
  return *(u16*)&h;
}
DEV float bf2f_s(short s) { return __uint_as_float(((u32)(u16)s) << 16); }

#define NB 8
#define NH 6
#define CTOT 192
#define HW 16384
#define QL2 72     // q/k LDS row stride (u16): 64-px window + 8 pad (16B-mult)
#define VTS2 40    // vt LDS per-col stride (u16): 32 ch + 8 pad (16B-mult)
// vt2 fragment-order layout: [b][nb=n>>7][w=(n>>5)&3][nt=(n>>4)&1][ks=c>>5][row=n&15][kq=(c>>3)&3][e=c&7]
#define VT2_PER_B 3145728   // 16384*192

// load 6 input floats (4 outputs + 2 halo cols) of one row, zero-padded
DEV void loadrow6(float* d, const float* __restrict__ in, int ar, int c0) {
  const bool rok = (ar >= 0) && (ar < 128);
  const float* rp = in + ar * 128;
  d[0] = (rok && c0 > 0) ? rp[c0 - 1] : 0.0f;
  float4 f0;
  if (rok) f0 = *(const float4*)(rp + c0);
  else     f0 = make_float4(0.f, 0.f, 0.f, 0.f);
  d[1] = f0.x; d[2] = f0.y; d[3] = f0.z; d[4] = f0.w;
  d[5] = (rok && (c0 + 4) < 128) ? rp[c0 + 4] : 0.0f;
}

// ---------------------------------------------------------------------------
// K1 (fused, v5): block = (b, head, 8-row stripe, 32-col quarter). Register
// diet vs v4: 4 cols/thread (ring 36 f32), sequential per-tensor conv, to get
// total regs (VGPR+acc) under the 128 cliff -> 4 blocks/CU resident.
// Per 2-row phase: stage q,k (64-px window) -> MFMA gram partial (waves 0,1);
// v -> vt2 in MFMA-fragment order (1KB-coalesced wave stores).
// ---------------------------------------------------------------------------
__global__ __launch_bounds__(256) void k1_fused(
    const float* __restrict__ x, const float* __restrict__ y,
    const float* __restrict__ wdw,
    u16* __restrict__ vt, float* __restrict__ gram,
    float* __restrict__ sqq, float* __restrict__ sqk)
{
  const int t   = threadIdx.x;
  const int bx  = blockIdx.x;          // 3072 = ((b*6+cg)*16+rg)*4+cp4
  const int cp4 = bx & 3;
  const int rg  = (bx >> 2) & 15;
  const int cg  = (bx >> 6) % 6;       // head
  const int b   = bx / 384;
  const int cl  = t >> 3;              // channel in head 0..31
  const int colgrp = t & 7;
  const int gc  = cg * 32 + cl;
  const int c0  = cp4 * 32 + colgrp * 4;
  const int r0  = rg * 8;
  const int bh  = b * NH + cg;
  const int l    = t & 63, w = t >> 6;
  const int arow = l & 15;
  const int kq8  = (l >> 4) << 3;

  __shared__ __align__(16) u16 q_lds[32 * QL2];
  __shared__ __align__(16) u16 k_lds[32 * QL2];
  __shared__ __align__(16) u16 vt_lds[2 * 32 * VTS2];
  __shared__ __align__(16) float gram_lds[1024];

  *(f32x4*)&gram_lds[t * 4] = (f32x4){0.f, 0.f, 0.f, 0.f};

  const float* __restrict__ xin = x + (((size_t)(b * CTOT + gc)) << 14);
  const float* __restrict__ yin = y + (((size_t)(b * CTOT + gc)) << 14);

  float wq[9], wk[9], wv[9];
#pragma unroll
  for (int i = 0; i < 9; ++i) {
    wq[i] = wdw[gc * 9 + i];
    wk[i] = wdw[(CTOT + gc) * 9 + i];
    wv[i] = wdw[(2 * CTOT + gc) * 9 + i];
  }

  float xb[3][6], yb[3][6];
  loadrow6(xb[0], xin, r0 - 1, c0);
  loadrow6(yb[0], yin, r0 - 1, c0);
  loadrow6(xb[1], xin, r0,     c0);
  loadrow6(yb[1], yin, r0,     c0);

  f32x4 acc[2][2] = {};
  float sq[2] = {0.f, 0.f}, sk[2] = {0.f, 0.f};

  // vt2 store roles (per phase): thread t owns (sub, col, 8-ch quarter)
  const int sub_s = t >> 7;
  const int col_s = (t >> 2) & 31;
  const int q_s   = t & 3;

#pragma unroll
  for (int ph = 0; ph < 4; ++ph) {
#pragma unroll
    for (int sub = 0; sub < 2; ++sub) {
      const int rr = ph * 2 + sub;
      const int r  = r0 + rr;
      // load next row into ring slot (used as tap dr=2 this iteration)
      loadrow6(xb[(rr + 2) % 3], xin, r + 1, c0);
      loadrow6(yb[(rr + 2) % 3], yin, r + 1, c0);

      // q conv (x)
      {
        float a[4];
#pragma unroll
        for (int j = 0; j < 4; ++j) a[j] = 0.f;
#pragma unroll
        for (int dr = 0; dr < 3; ++dr)
#pragma unroll
          for (int j = 0; j < 4; ++j)
#pragma unroll
            for (int dc = 0; dc < 3; ++dc)
              a[j] = fmaf(wq[dr * 3 + dc], xb[(rr + dr) % 3][j + dc], a[j]);
        u16* qp = &q_lds[cl * QL2 + sub * 32 + colgrp * 4];
#pragma unroll
        for (int j = 0; j < 4; ++j) qp[j] = f2bf(a[j]);
      }
      // k conv (y)
      {
        float a[4];
#pragma unroll
        for (int j = 0; j < 4; ++j) a[j] = 0.f;
#pragma unroll
        for (int dr = 0; dr < 3; ++dr)
#pragma unroll
          for (int j = 0; j < 4; ++j)
#pragma unroll
            for (int dc = 0; dc < 3; ++dc)
              a[j] = fmaf(wk[dr * 3 + dc], yb[(rr + dr) % 3][j + dc], a[j]);
        u16* kp = &k_lds[cl * QL2 + sub * 32 + colgrp * 4];
#pragma unroll
        for (int j = 0; j < 4; ++j) kp[j] = f2bf(a[j]);
      }
      // v conv (y) -> transpose-staging LDS
      {
        float a[4];
#pragma unroll
        for (int j = 0; j < 4; ++j) a[j] = 0.f;
#pragma unroll
        for (int dr = 0; dr < 3; ++dr)
#pragma unroll
          for (int j = 0; j < 4; ++j)
#pragma unroll
            for (int dc = 0; dc < 3; ++dc)
              a[j] = fmaf(wv[dr * 3 + dc], yb[(rr + dr) % 3][j + dc], a[j]);
#pragma unroll
        for (int j = 0; j < 4; ++j)
          vt_lds[(sub * 32 + colgrp * 4 + j) * VTS2 + cl] = f2bf(a[j]);
      }
    }
    __syncthreads();

    // gram partial via MFMA (waves 0,1: 64-px window, wave w owns px w*32..+31)
    if (w < 2) {
      short8 a2[2], b2[2];
#pragma unroll
      for (int tc = 0; tc < 2; ++tc) {
        a2[tc] = *(const short8*)&q_lds[(tc * 16 + arow) * QL2 + w * 32 + kq8];
        b2[tc] = *(const short8*)&k_lds[(tc * 16 + arow) * QL2 + w * 32 + kq8];
      }
#pragma unroll
      for (int tc = 0; tc < 2; ++tc)
#pragma unroll
        for (int j = 0; j < 8; ++j) {
          float fa = bf2f_s(a2[tc][j]); sq[tc] = fmaf(fa, fa, sq[tc]);
          float fb = bf2f_s(b2[tc][j]); sk[tc] = fmaf(fb, fb, sk[tc]);
        }
#pragma unroll
      for (int tc = 0; tc < 2; ++tc)
#pragma unroll
        for (int td = 0; td < 2; ++td)
          acc[tc][td] = __builtin_amdgcn_mfma_f32_16x16x32_bf16(a2[tc], b2[td], acc[tc][td], 0, 0, 0);
    }

    // vt2 store: fragment-order layout; wave stores are 1KB-contiguous
    {
      const int r_s = r0 + ph * 2 + sub_s;
      short8 d0 = *(short8*)&vt_lds[(sub_s * 32 + col_s) * VTS2 + q_s * 8];
      size_t flat = (size_t)b * VT2_PER_B +
          ((((((size_t)(r_s * 4 + cp4)) * 2 + (col_s >> 4)) * 6 + cg) * 16 + (col_s & 15)) * 32) +
          q_s * 8;
      *(short8*)(vt + flat) = d0;
    }
    __syncthreads();
  }

  // block-level gram reduction in LDS, then one global atomicAdd per element
  if (w < 2) {
#pragma unroll
    for (int tc = 0; tc < 2; ++tc)
#pragma unroll
      for (int td = 0; td < 2; ++td)
#pragma unroll
        for (int r2 = 0; r2 < 4; ++r2) {
          int c = tc * 16 + (l >> 4) * 4 + r2;
          int d = td * 16 + arow;
          atomicAdd(&gram_lds[c * 32 + d], acc[tc][td][r2]);
        }
  }
  __syncthreads();
#pragma unroll
  for (int i = 0; i < 4; ++i)
    atomicAdd(gram + (size_t)bh * 1024 + t * 4 + i, gram_lds[t * 4 + i]);

  if (w < 2) {
#pragma unroll
    for (int tc = 0; tc < 2; ++tc) {
      sq[tc] += __shfl_xor(sq[tc], 16);
      sq[tc] += __shfl_xor(sq[tc], 32);
      sk[tc] += __shfl_xor(sk[tc], 16);
      sk[tc] += __shfl_xor(sk[tc], 32);
    }
    if ((l >> 4) == 0) {
#pragma unroll
      for (int tc = 0; tc < 2; ++tc) {
        atomicAdd(sqq + bh * 32 + tc * 16 + arow, sq[tc]);
        atomicAdd(sqk + bh * 32 + tc * 16 + arow, sk[tc]);
      }
    }
  }
}

// ---------------------------------------------------------------------------
// K2b: logits = gram/(|q||k|)*temp, row-softmax, fold 1x1 proj:
//   W2[b][o][h*32+d] = sum_c wp[o][h*32+c] * A[c][d]  (bf16 out)
// ---------------------------------------------------------------------------
__global__ __launch_bounds__(256) void k2b_w2(
    const float* __restrict__ gram, const float* __restrict__ sqq,
    const float* __restrict__ sqk, const float* __restrict__ wp,
    const float* __restrict__ temp, u16* __restrict__ W2)
{
  __shared__ float Ls[32][33];
  __shared__ float As[32][33];
  __shared__ float wl[192 * 32];
  __shared__ float nq[32], nk[32];
  const int t = threadIdx.x;
  const int bh = blockIdx.x, b = bh / 6, h = bh % 6;
  const float tmp = temp[h];
  if (t < 32) nq[t] = fmaxf(sqrtf(sqq[bh * 32 + t]), 1e-12f);
  else if (t < 64) nk[t - 32] = fmaxf(sqrtf(sqk[bh * 32 + t - 32]), 1e-12f);
  __syncthreads();
#pragma unroll
  for (int i = 0; i < 4; ++i) {
    int idx = i * 256 + t, c = idx >> 5, d = idx & 31;
    Ls[c][d] = gram[(size_t)bh * 1024 + idx] / (nq[c] * nk[d]) * tmp;
  }
  __syncthreads();
  if (t < 32) {
    float m = -1e30f;
#pragma unroll
    for (int d = 0; d < 32; ++d) m = fmaxf(m, Ls[t][d]);
    float s = 0.f;
#pragma unroll
    for (int d = 0; d < 32; ++d) s += expf(Ls[t][d] - m);
    float inv = 1.0f / s;
#pragma unroll
    for (int d = 0; d < 32; ++d) As[t][d] = expf(Ls[t][d] - m) * inv;
  }
  for (int i = 0; i < 24; ++i) {
    int idx = i * 256 + t, o = idx >> 5, c = idx & 31;
    wl[idx] = wp[o * 192 + h * 32 + c];
  }
  __syncthreads();
  for (int i = 0; i < 24; ++i) {
    int idx = i * 256 + t, o = idx >> 5, d = idx & 31;
    float a = 0.f;
#pragma unroll
    for (int c = 0; c < 32; ++c) a = fmaf(wl[o * 32 + c], As[c][d], a);
    W2[((size_t)(b * 192 + o)) * 192 + h * 32 + d] = f2bf(a);
  }
}

// ---------------------------------------------------------------------------
// K3: out[b][o][n] = sum_c W2[b][o][c] * v[b][c][n] via MFMA 16x16x32 bf16.
// A = W2 [o][c] k-contiguous; B = vt2 in fragment order -> each wave B-load
// is one fully-coalesced 1KB read.
// ---------------------------------------------------------------------------
__global__ __launch_bounds__(256) void k3_gemm(
    const u16* __restrict__ W2, const u16* __restrict__ vt,
    float* __restrict__ out)
{
  const int t = threadIdx.x, l = t & 63, w = t >> 6;
  const int bx = blockIdx.x;
  const int b  = bx >> 7, nb = bx & 127;
  const int row = l & 15;
  const int kq8 = (l >> 4) * 8;
  const u16* w2b = W2 + (size_t)b * 192 * 192;
  const u16* vtb = vt + (size_t)b * VT2_PER_B;
  const int n0 = nb * 128 + w * 32;

  f32x4 acc[12][2] = {};

  for (int ks = 0; ks < 6; ++ks) {
    short8 bf[2];
#pragma unroll
    for (int nt = 0; nt < 2; ++nt)
      bf[nt] = *(const short8*)(vtb +
          ((size_t)(((nb * 4 + w) * 2 + nt) * 6 + ks)) * 512 + row * 32 + kq8);
#pragma unroll
    for (int ot = 0; ot < 12; ++ot) {
      short8 af = *(const short8*)(w2b + (size_t)(ot * 16 + row) * 192 + ks * 32 + kq8);
#pragma unroll
      for (int nt = 0; nt < 2; ++nt)
        acc[ot][nt] = __builtin_amdgcn_mfma_f32_16x16x32_bf16(af, bf[nt], acc[ot][nt], 0, 0, 0);
    }
  }

  float* ob = out + ((size_t)b * 192) * 16384;
#pragma unroll
  for (int ot = 0; ot < 12; ++ot)
#pragma unroll
    for (int nt = 0; nt < 2; ++nt)
#pragma unroll
      for (int rr = 0; rr < 4; ++rr) {
        int o = ot * 16 + (l >> 4) * 4 + rr;
        int n = n0 + nt * 16 + row;
        ob[(size_t)o * 16384 + n] = acc[ot][nt][rr];
      }
}

// ---------------------------------------------------------------------------
extern "C" void kernel_launch(void* const* d_in, const int* in_sizes, int n_in,
                              void* d_out, int out_size, void* d_ws, size_t ws_size,
                              hipStream_t stream)
{
  const float* x    = (const float*)d_in[0];
  const float* y    = (const float*)d_in[1];
  const float* wdw  = (const float*)d_in[2];
  const float* wp   = (const float*)d_in[3];
  const float* temp = (const float*)d_in[4];

  char* ws = (char*)d_ws;
  const size_t VT = (size_t)NB * VT2_PER_B * 2;   // 50,331,648 bytes
  u16*   vt   = (u16*)(ws);
  float* gram = (float*)(ws + VT);                       // 48*1024*4 = 196608
  float* sqq  = (float*)(ws + VT + 196608);              // 6144
  float* sqk  = (float*)(ws + VT + 196608 + 6144);       // 6144
  u16*   W2   = (u16*)(ws + VT + 196608 + 12288);        // 8*192*192*2
  float* out  = (float*)d_out;

  hipMemsetAsync(ws + VT, 0, 208896, stream);
  k1_fused<<<3072, 256, 0, stream>>>(x, y, wdw, vt, gram, sqq, sqk);
  k2b_w2<<<48, 256, 0, stream>>>(gram, sqq, sqk, wp, temp, W2);
  k3_gemm<<<1024, 256, 0, stream>>>(W2, vt, out);
}

// Round 9
// 185.996 us; speedup vs baseline: 1.1404x; 1.1404x over previous
//
#include <hip/hip_runtime.h>
#include <hip/hip_bf16.h>

#define DEV __device__ __forceinline__

typedef unsigned short u16;
typedef unsigned int u32;
typedef __attribute__((ext_vector_type(8))) short short8;
typedef __attribute__((ext_vector_type(4))) float f32x4;

DEV u16 f2bf(float f) {
  __hip_bfloat16 h = __float2bfloat16(f);   // RNE; pairs into v_cvt_pk_bf16_f32
  return *(u16*)&h;
}
DEV float bf2f_s(short s) { return __uint_as_float(((u32)(u16)s) << 16); }

#define NB 8
#define NH 6
#define CTOT 192
#define HW 16384
#define QLD 136    // q/k LDS row stride (u16): 128-pixel K-window + 8 pad
#define VTS 34     // vt LDS per-col stride (u16): 32 ch + 2 pad

// load 10 input floats (8 outputs + 2 halo cols) of one row, zero-padded
DEV void loadrow10(float* d, const float* __restrict__ in, int ar, int c0) {
  const bool rok = (ar >= 0) && (ar < 128);
  const float* rp = in + ar * 128;
  d[0] = (rok && c0 > 0) ? rp[c0 - 1] : 0.0f;
  float4 f0, f1;
  if (rok) { f0 = *(const float4*)(rp + c0); f1 = *(const float4*)(rp + c0 + 4); }
  else { f0 = make_float4(0.f,0.f,0.f,0.f); f1 = f0; }
  d[1] = f0.x; d[2] = f0.y; d[3] = f0.z; d[4] = f0.w;
  d[5] = f1.x; d[6] = f1.y; d[7] = f1.z; d[8] = f1.w;
  d[9] = (rok && (c0 + 8) < 128) ? rp[c0 + 8] : 0.0f;
}

// ---------------------------------------------------------------------------
// K1 (fused, v6): R6 geometry (1536 blocks, 64-col, 8 cols/thread, 3-slot row
// ring) with the vt GLOBAL STORE DECOUPLED from the barrier: the MFMA phase
// only reads vt_lds into registers; the store issues at the start of the NEXT
// conv phase, so the compiler's s_waitcnt vmcnt(0) before each s_barrier no
// longer serializes a scattered-store retire into every phase (the theory for
// the 123us plateau: 8 phases x store-drain latency).
// ---------------------------------------------------------------------------
__global__ __launch_bounds__(256) void k1_fused(
    const float* __restrict__ x, const float* __restrict__ y,
    const float* __restrict__ wdw,
    u16* __restrict__ vt, float* __restrict__ gram,
    float* __restrict__ sqq, float* __restrict__ sqk)
{
  const int t   = threadIdx.x;
  const int bx  = blockIdx.x;          // 1536 = ((b*6+cg)*16+rg)*2+chp
  const int chp = bx & 1;
  const int rg  = (bx >> 1) & 15;
  const int cg  = (bx >> 5) % 6;       // head
  const int b   = bx / 192;
  const int cl  = t >> 3;              // channel in head 0..31
  const int colgrp = t & 7;
  const int gc  = cg * 32 + cl;
  const int c0  = chp * 64 + colgrp * 8;
  const int r0  = rg * 8;
  const int bh  = b * NH + cg;
  const int l    = t & 63, w = t >> 6;
  const int arow = l & 15;
  const int koff = w * 32 + ((l >> 4) << 3);

  __shared__ __align__(16) u16 q_lds[32 * QLD];
  __shared__ __align__(16) u16 k_lds[32 * QLD];
  __shared__ __align__(16) u16 vt_lds[2 * 64 * VTS];
  __shared__ __align__(16) float gram_lds[1024];

  *(f32x4*)&gram_lds[t * 4] = (f32x4){0.f, 0.f, 0.f, 0.f};

  const float* __restrict__ xin = x + (((size_t)(b * CTOT + gc)) << 14);
  const float* __restrict__ yin = y + (((size_t)(b * CTOT + gc)) << 14);

  float wq[9], wk[9], wv[9];
#pragma unroll
  for (int i = 0; i < 9; ++i) {
    wq[i] = wdw[gc * 9 + i];
    wk[i] = wdw[(CTOT + gc) * 9 + i];
    wv[i] = wdw[(2 * CTOT + gc) * 9 + i];
  }

  float xb[3][10], yb[3][10];
  loadrow10(xb[0], xin, r0 - 1, c0);
  loadrow10(yb[0], yin, r0 - 1, c0);
  loadrow10(xb[1], xin, r0,     c0);
  loadrow10(yb[1], yin, r0,     c0);

  f32x4 acc[2][2] = {};
  float sq[2] = {0.f, 0.f}, sk[2] = {0.f, 0.f};

  // deferred vt store state (filled in MFMA phase, stored next conv phase)
  short8 vd0, vd1;
  size_t voff = 0;
  const int sub_s  = t >> 7;            // vt-read roles
  const int col_s  = (t >> 1) & 63;
  const int half_s = (t & 1) * 16;

#pragma unroll
  for (int ph = 0; ph < 4; ++ph) {
    // issue the deferred vt store from the PREVIOUS phase: it retires during
    // this phase's ~1100cy of conv VALU instead of stalling a barrier.
    if (ph > 0) {
      *(short8*)(vt + voff)     = vd0;
      *(short8*)(vt + voff + 8) = vd1;
    }
#pragma unroll
    for (int sub = 0; sub < 2; ++sub) {
      const int rr = ph * 2 + sub;
      const int r  = r0 + rr;
      // ring-load the next input row (used as tap dr=2 this iteration)
      loadrow10(xb[(rr + 2) % 3], xin, r + 1, c0);
      loadrow10(yb[(rr + 2) % 3], yin, r + 1, c0);

      float aq[8], ak[8], av[8];
#pragma unroll
      for (int j = 0; j < 8; ++j) { aq[j] = 0.f; ak[j] = 0.f; av[j] = 0.f; }
#pragma unroll
      for (int dr = 0; dr < 3; ++dr) {
#pragma unroll
        for (int j = 0; j < 8; ++j)
#pragma unroll
          for (int dc = 0; dc < 3; ++dc) {
            aq[j] = fmaf(wq[dr * 3 + dc], xb[(rr + dr) % 3][j + dc], aq[j]);
            ak[j] = fmaf(wk[dr * 3 + dc], yb[(rr + dr) % 3][j + dc], ak[j]);
            av[j] = fmaf(wv[dr * 3 + dc], yb[(rr + dr) % 3][j + dc], av[j]);
          }
      }
      short8 pq, pk;
#pragma unroll
      for (int j = 0; j < 8; ++j) {
        pq[j] = (short)f2bf(aq[j]);
        pk[j] = (short)f2bf(ak[j]);
      }
      *(short8*)&q_lds[cl * QLD + sub * 64 + colgrp * 8] = pq;
      *(short8*)&k_lds[cl * QLD + sub * 64 + colgrp * 8] = pk;
#pragma unroll
      for (int j = 0; j < 8; ++j)
        vt_lds[sub * 64 * VTS + (colgrp * 8 + j) * VTS + cl] = f2bf(av[j]);
    }
    __syncthreads();

    // gram partial via MFMA over the 128-pixel window + sum-of-squares
    short8 a2[2], b2[2];
#pragma unroll
    for (int tc = 0; tc < 2; ++tc) {
      a2[tc] = *(const short8*)&q_lds[(tc * 16 + arow) * QLD + koff];
      b2[tc] = *(const short8*)&k_lds[(tc * 16 + arow) * QLD + koff];
    }
#pragma unroll
    for (int tc = 0; tc < 2; ++tc)
#pragma unroll
      for (int j = 0; j < 8; ++j) {
        float fa = bf2f_s(a2[tc][j]); sq[tc] = fmaf(fa, fa, sq[tc]);
        float fb = bf2f_s(b2[tc][j]); sk[tc] = fmaf(fb, fb, sk[tc]);
      }
#pragma unroll
    for (int tc = 0; tc < 2; ++tc)
#pragma unroll
      for (int td = 0; td < 2; ++td)
        acc[tc][td] = __builtin_amdgcn_mfma_f32_16x16x32_bf16(a2[tc], b2[td], acc[tc][td], 0, 0, 0);

    // vt: read LDS transpose into REGISTERS only; store is deferred
    {
      const int r = r0 + ph * 2 + sub_s;
      const int base = sub_s * 64 * VTS + col_s * VTS + half_s;
      vd0 = *(short8*)&vt_lds[base];
      vd1 = *(short8*)&vt_lds[base + 8];
      voff = ((size_t)(b * HW + r * 128 + chp * 64 + col_s)) * CTOT + cg * 32 + half_s;
    }
    __syncthreads();
  }
  // final deferred vt store
  *(short8*)(vt + voff)     = vd0;
  *(short8*)(vt + voff + 8) = vd1;

  // block-level gram reduction in LDS, then one global atomicAdd per element
#pragma unroll
  for (int tc = 0; tc < 2; ++tc)
#pragma unroll
    for (int td = 0; td < 2; ++td)
#pragma unroll
      for (int r2 = 0; r2 < 4; ++r2) {
        int c = tc * 16 + (l >> 4) * 4 + r2;
        int d = td * 16 + arow;
        atomicAdd(&gram_lds[c * 32 + d], acc[tc][td][r2]);
      }
  __syncthreads();
#pragma unroll
  for (int i = 0; i < 4; ++i)
    atomicAdd(gram + (size_t)bh * 1024 + t * 4 + i, gram_lds[t * 4 + i]);

#pragma unroll
  for (int tc = 0; tc < 2; ++tc) {
    sq[tc] += __shfl_xor(sq[tc], 16);
    sq[tc] += __shfl_xor(sq[tc], 32);
    sk[tc] += __shfl_xor(sk[tc], 16);
    sk[tc] += __shfl_xor(sk[tc], 32);
  }
  if ((l >> 4) == 0) {
#pragma unroll
    for (int tc = 0; tc < 2; ++tc) {
      atomicAdd(sqq + bh * 32 + tc * 16 + arow, sq[tc]);
      atomicAdd(sqk + bh * 32 + tc * 16 + arow, sk[tc]);
    }
  }
}

// ---------------------------------------------------------------------------
// K2b: logits = gram/(|q||k|)*temp, row-softmax, fold 1x1 proj:
//   W2[b][o][h*32+d] = sum_c wp[o][h*32+c] * A[c][d]  (bf16 out)
// ---------------------------------------------------------------------------
__global__ __launch_bounds__(256) void k2b_w2(
    const float* __restrict__ gram, const float* __restrict__ sqq,
    const float* __restrict__ sqk, const float* __restrict__ wp,
    const float* __restrict__ temp, u16* __restrict__ W2)
{
  __shared__ float Ls[32][33];
  __shared__ float As[32][33];
  __shared__ float wl[192 * 32];
  __shared__ float nq[32], nk[32];
  const int t = threadIdx.x;
  const int bh = blockIdx.x, b = bh / 6, h = bh % 6;
  const float tmp = temp[h];
  if (t < 32) nq[t] = fmaxf(sqrtf(sqq[bh * 32 + t]), 1e-12f);
  else if (t < 64) nk[t - 32] = fmaxf(sqrtf(sqk[bh * 32 + t - 32]), 1e-12f);
  __syncthreads();
#pragma unroll
  for (int i = 0; i < 4; ++i) {
    int idx = i * 256 + t, c = idx >> 5, d = idx & 31;
    Ls[c][d] = gram[(size_t)bh * 1024 + idx] / (nq[c] * nk[d]) * tmp;
  }
  __syncthreads();
  if (t < 32) {
    float m = -1e30f;
#pragma unroll
    for (int d = 0; d < 32; ++d) m = fmaxf(m, Ls[t][d]);
    float s = 0.f;
#pragma unroll
    for (int d = 0; d < 32; ++d) s += expf(Ls[t][d] - m);
    float inv = 1.0f / s;
#pragma unroll
    for (int d = 0; d < 32; ++d) As[t][d] = expf(Ls[t][d] - m) * inv;
  }
  for (int i = 0; i < 24; ++i) {
    int idx = i * 256 + t, o = idx >> 5, c = idx & 31;
    wl[idx] = wp[o * 192 + h * 32 + c];
  }
  __syncthreads();
  for (int i = 0; i < 24; ++i) {
    int idx = i * 256 + t, o = idx >> 5, d = idx & 31;
    float a = 0.f;
#pragma unroll
    for (int c = 0; c < 32; ++c) a = fmaf(wl[o * 32 + c], As[c][d], a);
    W2[((size_t)(b * 192 + o)) * 192 + h * 32 + d] = f2bf(a);
  }
}

// ---------------------------------------------------------------------------
// K3: out[b][o][n] = sum_c W2[b][o][c] * v[b][c][n] via MFMA 16x16x32 bf16.
// A = W2 [o][c] k-contiguous, B = vt [n][c] k-contiguous: direct 16B loads.
// ---------------------------------------------------------------------------
__global__ __launch_bounds__(256) void k3_gemm(
    const u16* __restrict__ W2, const u16* __restrict__ vt,
    float* __restrict__ out)
{
  const int t = threadIdx.x, l = t & 63, w = t >> 6;
  const int bx = blockIdx.x;
  const int b  = bx >> 7, nb = bx & 127;
  const int row = l & 15;
  const int kq  = (l >> 4) * 8;
  const u16* w2b = W2 + (size_t)b * 192 * 192;
  const u16* vtb = vt + ((size_t)b << 14) * 192;
  const int n0 = nb * 128 + w * 32;

  f32x4 acc[12][2] = {};

  for (int ks = 0; ks < 6; ++ks) {
    const int kb = ks * 32 + kq;
    short8 bf[2];
#pragma unroll
    for (int nt = 0; nt < 2; ++nt)
      bf[nt] = *(const short8*)(vtb + (size_t)(n0 + nt * 16 + row) * 192 + kb);
#pragma unroll
    for (int ot = 0; ot < 12; ++ot) {
      short8 af = *(const short8*)(w2b + (size_t)(ot * 16 + row) * 192 + kb);
#pragma unroll
      for (int nt = 0; nt < 2; ++nt)
        acc[ot][nt] = __builtin_amdgcn_mfma_f32_16x16x32_bf16(af, bf[nt], acc[ot][nt], 0, 0, 0);
    }
  }

  float* ob = out + ((size_t)b * 192) * 16384;
#pragma unroll
  for (int ot = 0; ot < 12; ++ot)
#pragma unroll
    for (int nt = 0; nt < 2; ++nt)
#pragma unroll
      for (int rr = 0; rr < 4; ++rr) {
        int o = ot * 16 + (l >> 4) * 4 + rr;
        int n = n0 + nt * 16 + row;
        ob[(size_t)o * 16384 + n] = acc[ot][nt][rr];
      }
}

// ---------------------------------------------------------------------------
extern "C" void kernel_launch(void* const* d_in, const int* in_sizes, int n_in,
                              void* d_out, int out_size, void* d_ws, size_t ws_size,
                              hipStream_t stream)
{
  const float* x    = (const float*)d_in[0];
  const float* y    = (const float*)d_in[1];
  const float* wdw  = (const float*)d_in[2];
  const float* wp   = (const float*)d_in[3];
  const float* temp = (const float*)d_in[4];

  char* ws = (char*)d_ws;
  const size_t VT = (size_t)NB * HW * CTOT * 2;   // 50,331,648 bytes
  u16*   vt   = (u16*)(ws);
  float* gram = (float*)(ws + VT);                       // 48*1024*4 = 196608
  float* sqq  = (float*)(ws + VT + 196608);              // 6144
  float* sqk  = (float*)(ws + VT + 196608 + 6144);       // 6144
  u16*   W2   = (u16*)(ws + VT + 196608 + 12288);        // 8*192*192*2
  float* out  = (float*)d_out;

  hipMemsetAsync(ws + VT, 0, 208896, stream);
  k1_fused<<<1536, 256, 0, stream>>>(x, y, wdw, vt, gram, sqq, sqk);
  k2b_w2<<<48, 256, 0, stream>>>(gram, sqq, sqk, wp, temp, W2);
  k3_gemm<<<1024, 256, 0, stream>>>(W2, vt, out);
}